// Round 3
// baseline (1487.402 us; speedup 1.0000x reference)
//
#include <hip/hip_runtime.h>
#include <hip/hip_bf16.h>

// ---- problem constants ----
#define NW 5
#define KS 5
#define SEQ 196
#define DIM 384
#define NSUP 25        // NW*KS support images
#define NQRY 75        // query images
#define NIMG 100       // NSUP + NQRY
#define LSUP 4900      // NSUP*SEQ support rows
#define BLOCK_W 980    // KS*SEQ rows per class block
#define PADW 1024      // padded class block for opt kernel
#define OPT_STEPS 15

static constexpr float TEMP_F = 0.0510310363f;
static constexpr float INV_T  = 1.0f / TEMP_F;   // ~19.5959
static constexpr float LR_F   = 0.1f;

typedef short v8s __attribute__((ext_vector_type(8)));   // 8 x bf16 frag (4 VGPRs)
typedef float v4f __attribute__((ext_vector_type(4)));   // 4 x f32 acc

__device__ inline unsigned short f2bf(float x) {
    unsigned int u = __float_as_uint(x);
    u += 0x7fffu + ((u >> 16) & 1u);
    return (unsigned short)(u >> 16);
}
__device__ inline float bf2f(unsigned short u) {
    return __uint_as_float(((unsigned int)u) << 16);
}

// ---------------------------------------------------------------------------
// Kernel 1: fused normalize of all 24500 rows -> bf16. One wave per row.
// rows [0,4900): sup_key -> Kb (pre-scaled by 1/T)
// rows [4900,9800): sup_qry -> Qall[0..4899]
// rows [9800,24500): qry -> Qall[4900..19599]
// ---------------------------------------------------------------------------
__global__ __launch_bounds__(256) void norm_all(const float* __restrict__ sup_key,
                                                const float* __restrict__ sup_qry,
                                                const float* __restrict__ qry,
                                                unsigned short* __restrict__ Kb,
                                                unsigned short* __restrict__ Qall) {
    int row = blockIdx.x * 4 + (threadIdx.x >> 6);
    int lane = threadIdx.x & 63;
    if (row >= 2 * LSUP + NQRY * SEQ) return;
    const float* src;
    unsigned short* dst;
    float scale;
    if (row < LSUP) {
        src = sup_key + (size_t)row * DIM;
        dst = Kb + (size_t)row * DIM;
        scale = INV_T;
    } else if (row < 2 * LSUP) {
        src = sup_qry + (size_t)(row - LSUP) * DIM;
        dst = Qall + (size_t)(row - LSUP) * DIM;
        scale = 1.0f;
    } else {
        src = qry + (size_t)(row - 2 * LSUP) * DIM;
        dst = Qall + (size_t)(row - LSUP) * DIM;
        scale = 1.0f;
    }
    float x[6];
    float s = 0.f;
    #pragma unroll
    for (int i = 0; i < 6; ++i) { x[i] = src[lane + 64 * i]; s += x[i] * x[i]; }
    #pragma unroll
    for (int m = 1; m < 64; m <<= 1) s += __shfl_xor(s, m);
    float sc = scale / fmaxf(sqrtf(s), 1e-8f);
    #pragma unroll
    for (int i = 0; i < 6; ++i) dst[lane + 64 * i] = f2bf(x[i] * sc);
}

// ---------------------------------------------------------------------------
// Kernel 2: MFMA fused exp-sum GEMM, A-in-registers / full-image-B-in-LDS.
//   R[img][r] = sum_qs exp( (Kn[r] . Qimg[qs]) / T )    (K pre-scaled by 1/T)
// Block: 512 thr = 8 waves, each wave owns 48 rows (3 m-tiles), full K=384
// held in registers (36 v8s frags). B staged in 3 col-passes of 80 qs.
// img<25 -> write bf16 to Rbf[b][w*1024+r] (masked rows -> 0)
// img>=25 -> write f32 to Rq[(img-25)*4900 + r]
// ---------------------------------------------------------------------------
#define QTILE 80
#define LDB   392   // LDS row stride in shorts (384+8): 16B aligned, balanced banks

__global__ __launch_bounds__(512, 2) void fused_gemm(
    const unsigned short* __restrict__ Kb,
    const unsigned short* __restrict__ Qall,
    float* __restrict__ Rq,
    unsigned short* __restrict__ Rbf)
{
    __shared__ __align__(16) unsigned short Bs[QTILE * LDB];  // 62720 B

    int t = threadIdx.x;
    int img = blockIdx.y;
    int wv = t >> 6, l = t & 63;
    int lo = l & 15, hi = l >> 4;
    const unsigned short* Q = Qall + (size_t)img * SEQ * DIM;
    int row0 = blockIdx.x * 384 + wv * 48;

    // --- load A fragments: 3 m-tiles x 12 k-tiles, once, from L2 ---
    v8s A[3][12];
    #pragma unroll
    for (int mm = 0; mm < 3; ++mm) {
        #pragma unroll
        for (int kk = 0; kk < 12; ++kk) {
            int gr = row0 + mm * 16 + lo;
            v8s z = {0, 0, 0, 0, 0, 0, 0, 0};
            A[mm][kk] = (gr < LSUP)
                ? *(const v8s*)(Kb + (size_t)gr * DIM + kk * 32 + hi * 8)
                : z;
        }
    }

    float srow[3][4];
    #pragma unroll
    for (int mm = 0; mm < 3; ++mm)
        #pragma unroll
        for (int j = 0; j < 4; ++j) srow[mm][j] = 0.f;

    for (int pass = 0; pass < 3; ++pass) {
        int qbase = pass * QTILE;
        int ntiles = (pass < 2) ? 5 : 3;
        int nstage = (pass < 2) ? QTILE : 48;
        // stage B tile
        for (int i = t; i < nstage * 48; i += 512) {
            int qs = i / 48, kc = i % 48;
            int gq = qbase + qs;
            float4 vv = make_float4(0.f, 0.f, 0.f, 0.f);
            if (gq < SEQ) vv = *(const float4*)(Q + (size_t)gq * DIM + kc * 8);
            *(float4*)(Bs + qs * LDB + kc * 8) = vv;
        }
        __syncthreads();

        for (int n = 0; n < ntiles; ++n) {
            v4f acc[3];
            #pragma unroll
            for (int mm = 0; mm < 3; ++mm) acc[mm] = (v4f){0.f, 0.f, 0.f, 0.f};
            const unsigned short* Bn = Bs + (n * 16 + lo) * LDB + hi * 8;
            #pragma unroll 4
            for (int kk = 0; kk < 12; ++kk) {
                v8s bb = *(const v8s*)(Bn + kk * 32);
                acc[0] = __builtin_amdgcn_mfma_f32_16x16x32_bf16(A[0][kk], bb, acc[0], 0, 0, 0);
                acc[1] = __builtin_amdgcn_mfma_f32_16x16x32_bf16(A[1][kk], bb, acc[1], 0, 0, 0);
                acc[2] = __builtin_amdgcn_mfma_f32_16x16x32_bf16(A[2][kk], bb, acc[2], 0, 0, 0);
            }
            bool ok = (qbase + n * 16 + lo) < SEQ;
            #pragma unroll
            for (int mm = 0; mm < 3; ++mm)
                #pragma unroll
                for (int j = 0; j < 4; ++j)
                    srow[mm][j] += ok ? __expf(acc[mm][j]) : 0.f;
        }
        __syncthreads();
    }

    // reduce across the 16 column lanes (lo); C/D layout: col=lo, row=hi*4+j
    #pragma unroll
    for (int m = 1; m < 16; m <<= 1)
        #pragma unroll
        for (int mm = 0; mm < 3; ++mm)
            #pragma unroll
            for (int j = 0; j < 4; ++j)
                srow[mm][j] += __shfl_xor(srow[mm][j], m);

    if (lo == 0) {
        #pragma unroll
        for (int mm = 0; mm < 3; ++mm) {
            #pragma unroll
            for (int j = 0; j < 4; ++j) {
                int r = row0 + mm * 16 + hi * 4 + j;
                if (r < LSUP) {
                    float val = srow[mm][j];
                    if (img < NSUP) {
                        if (r / SEQ == img) val = 0.f;        // block-diag mask
                        int w = r / BLOCK_W, rr = r - w * BLOCK_W;
                        Rbf[(size_t)img * (NW * PADW) + w * PADW + rr] = f2bf(val);
                    } else {
                        Rq[(size_t)(img - NSUP) * LSUP + r] = val;
                    }
                }
            }
        }
    }
}

// ---------------------------------------------------------------------------
// Kernel 3: whole 15-step SGD in ONE 1024-thread block.
// Rbf layout: [b][w*1024 + r], bf16, pads (r in [980,1024)) zeroed here.
//   e[ls]=exp(v/T); D[b][w]=sum e*R; cf=(D/sumD - onehot)*(INV_T/25)/D;
//   v -= LR * e * sum_b cf[b][w]*R[b][ls]
// ---------------------------------------------------------------------------
__global__ __launch_bounds__(1024) void opt_all(unsigned short* __restrict__ Rbf,
                                                const int* __restrict__ labels,
                                                float* __restrict__ v_out) {
    __shared__ float v_s[NW * PADW];
    __shared__ float e_s[NW * PADW];
    __shared__ float D_s[128];
    __shared__ float cf_s[128];
    int t = threadIdx.x;
    int wave = t >> 6, lane = t & 63;

    // zero Rbf pads (GEMM never writes r in [980,1024))
    for (int i = t; i < NSUP * NW * (PADW - BLOCK_W); i += 1024) {
        int b = i / (NW * (PADW - BLOCK_W));
        int rem = i % (NW * (PADW - BLOCK_W));
        int w = rem / (PADW - BLOCK_W), r = BLOCK_W + rem % (PADW - BLOCK_W);
        Rbf[(size_t)b * (NW * PADW) + w * PADW + r] = 0;
    }
    for (int i = t; i < NW * PADW; i += 1024) {
        v_s[i] = 0.f;
        e_s[i] = ((i & (PADW - 1)) < BLOCK_W) ? 1.f : 0.f;
    }
    __syncthreads();

    // D-sum phase (shared by init and steps)
    auto phase2 = [&]() {
        for (int p = wave; p < 125; p += 16) {
            int b = p / 5, w = p % 5;
            const unsigned short* R = Rbf + (size_t)b * (NW * PADW) + w * PADW;
            const float* e = e_s + w * PADW;
            float s = 0.f;
            #pragma unroll
            for (int it = 0; it < 2; ++it) {
                int base = it * 512 + lane * 8;
                uint4 u = *(const uint4*)(R + base);
                s += bf2f((unsigned short)(u.x & 0xffff)) * e[base + 0];
                s += bf2f((unsigned short)(u.x >> 16))    * e[base + 1];
                s += bf2f((unsigned short)(u.y & 0xffff)) * e[base + 2];
                s += bf2f((unsigned short)(u.y >> 16))    * e[base + 3];
                s += bf2f((unsigned short)(u.z & 0xffff)) * e[base + 4];
                s += bf2f((unsigned short)(u.z >> 16))    * e[base + 5];
                s += bf2f((unsigned short)(u.w & 0xffff)) * e[base + 6];
                s += bf2f((unsigned short)(u.w >> 16))    * e[base + 7];
            }
            #pragma unroll
            for (int m = 1; m < 64; m <<= 1) s += __shfl_xor(s, m);
            if (lane == 0) D_s[p] = s;
        }
    };

    phase2();          // D_0 (e = 1)
    __syncthreads();

    for (int s = 0; s < OPT_STEPS; ++s) {
        if (t < NSUP) {
            int b = t;
            float Dsum = 0.f;
            #pragma unroll
            for (int w = 0; w < NW; ++w) Dsum += D_s[b * 5 + w];
            int y = labels[b];
            #pragma unroll
            for (int w = 0; w < NW; ++w) {
                float Dv = D_s[b * 5 + w];
                cf_s[b * 5 + w] = ((Dv / Dsum) - (w == y ? 1.f : 0.f)) * (INV_T / 25.f) / Dv;
            }
        }
        __syncthreads();

        if (t < BLOCK_W) {
            #pragma unroll
            for (int w = 0; w < NW; ++w) {
                int idx = w * PADW + t;
                float g = 0.f;
                #pragma unroll
                for (int b = 0; b < NSUP; ++b)
                    g += cf_s[b * 5 + w] * bf2f(Rbf[(size_t)b * (NW * PADW) + idx]);
                float vv = v_s[idx] - LR_F * e_s[idx] * g;
                v_s[idx] = vv;
                e_s[idx] = __expf(vv * INV_T);
            }
        }
        __syncthreads();

        if (s < OPT_STEPS - 1) {
            phase2();
            __syncthreads();
        }
    }

    if (t < BLOCK_W) {
        #pragma unroll
        for (int w = 0; w < NW; ++w) v_out[w * BLOCK_W + t] = v_s[w * PADW + t];
    }
}

// ---------------------------------------------------------------------------
// Kernel 4: out[qb][w] = log( sum_{r in w} e^{v/T} * Rq[qb][w*980+r] )
// ---------------------------------------------------------------------------
__global__ __launch_bounds__(256) void final_pred(const float* __restrict__ Rq,
                                                  const float* __restrict__ v,
                                                  float* __restrict__ out) {
    __shared__ float wsum[4];
    int blk = blockIdx.x;           // qb*5 + w
    int qb = blk / 5, w = blk % 5;
    const float* R  = Rq + (size_t)qb * LSUP + w * BLOCK_W;
    const float* vb = v + w * BLOCK_W;
    int t = threadIdx.x;
    float p = 0.f;
    for (int i = t; i < BLOCK_W; i += 256) p += __expf(vb[i] * INV_T) * R[i];
    #pragma unroll
    for (int off = 32; off; off >>= 1) p += __shfl_down(p, off);
    if ((t & 63) == 0) wsum[t >> 6] = p;
    __syncthreads();
    if (t == 0) out[blk] = logf(wsum[0] + wsum[1] + wsum[2] + wsum[3]);
}

// ---------------------------------------------------------------------------
extern "C" void kernel_launch(void* const* d_in, const int* in_sizes, int n_in,
                              void* d_out, int out_size, void* d_ws, size_t ws_size,
                              hipStream_t stream) {
    const float* sup_key = (const float*)d_in[0];   // [25,196,384]
    const float* sup_qry = (const float*)d_in[1];   // [25,196,384]
    const float* qry     = (const float*)d_in[2];   // [75,196,384]
    const int*   labels  = (const int*)d_in[3];     // [25]
    float* out = (float*)d_out;                     // [75,5]

    char* ws = (char*)d_ws;
    size_t off = 0;
    auto take = [&](size_t bytes) {
        char* p = ws + off;
        off = (off + bytes + 255) & ~(size_t)255;
        return p;
    };
    unsigned short* Kb   = (unsigned short*)take((size_t)LSUP * DIM * 2);
    unsigned short* Qall = (unsigned short*)take((size_t)NIMG * SEQ * DIM * 2);
    float*          Rq   = (float*)take((size_t)NQRY * LSUP * 4);
    unsigned short* Rbf  = (unsigned short*)take((size_t)NSUP * NW * PADW * 2);
    float*          v    = (float*)take((size_t)LSUP * 4);

    int nrows = 2 * LSUP + NQRY * SEQ;              // 24500
    norm_all<<<(nrows + 3) / 4, 256, 0, stream>>>(sup_key, sup_qry, qry, Kb, Qall);

    fused_gemm<<<dim3(13, NIMG), 512, 0, stream>>>(Kb, Qall, Rq, Rbf);

    opt_all<<<1, 1024, 0, stream>>>(Rbf, labels, v);

    final_pred<<<NQRY * NW, 256, 0, stream>>>(Rq, v, out);
}

// Round 4
// 502.017 us; speedup vs baseline: 2.9629x; 2.9629x over previous
//
#include <hip/hip_runtime.h>
#include <hip/hip_bf16.h>

// ---- problem constants ----
#define NW 5
#define KS 5
#define SEQ 196
#define DIM 384
#define NSUP 25        // NW*KS support images
#define NQRY 75        // query images
#define NIMG 100       // NSUP + NQRY
#define LSUP 4900      // NSUP*SEQ support rows
#define BLOCK_W 980    // KS*SEQ rows per class block
#define PADW 1024      // padded class block for opt kernel
#define OPT_STEPS 15

static constexpr float TEMP_F = 0.0510310363f;
static constexpr float INV_T  = 1.0f / TEMP_F;   // ~19.5959
static constexpr float LR_F   = 0.1f;

typedef short v8s __attribute__((ext_vector_type(8)));   // 8 x bf16 frag (4 VGPRs)
typedef float v4f __attribute__((ext_vector_type(4)));   // 4 x f32 acc

__device__ inline unsigned short f2bf(float x) {
    unsigned int u = __float_as_uint(x);
    u += 0x7fffu + ((u >> 16) & 1u);
    return (unsigned short)(u >> 16);
}
__device__ inline float bf2f(unsigned int u) {
    return __uint_as_float(u << 16);
}
__device__ inline void unpack8(uint4 u, float* f) {
    f[0] = bf2f(u.x & 0xffffu); f[1] = bf2f(u.x >> 16);
    f[2] = bf2f(u.y & 0xffffu); f[3] = bf2f(u.y >> 16);
    f[4] = bf2f(u.z & 0xffffu); f[5] = bf2f(u.z >> 16);
    f[6] = bf2f(u.w & 0xffffu); f[7] = bf2f(u.w >> 16);
}

// ---------------------------------------------------------------------------
// Kernel 1: fused normalize of all 24500 rows -> bf16. One wave per row.
// rows [0,4900): sup_key -> Kb (pre-scaled by 1/T)
// rows [4900,9800): sup_qry -> Qall[0..4899]
// rows [9800,24500): qry -> Qall[4900..19599]
// ---------------------------------------------------------------------------
__global__ __launch_bounds__(256) void norm_all(const float* __restrict__ sup_key,
                                                const float* __restrict__ sup_qry,
                                                const float* __restrict__ qry,
                                                unsigned short* __restrict__ Kb,
                                                unsigned short* __restrict__ Qall) {
    int row = blockIdx.x * 4 + (threadIdx.x >> 6);
    int lane = threadIdx.x & 63;
    if (row >= 2 * LSUP + NQRY * SEQ) return;
    const float* src;
    unsigned short* dst;
    float scale;
    if (row < LSUP) {
        src = sup_key + (size_t)row * DIM;
        dst = Kb + (size_t)row * DIM;
        scale = INV_T;
    } else if (row < 2 * LSUP) {
        src = sup_qry + (size_t)(row - LSUP) * DIM;
        dst = Qall + (size_t)(row - LSUP) * DIM;
        scale = 1.0f;
    } else {
        src = qry + (size_t)(row - 2 * LSUP) * DIM;
        dst = Qall + (size_t)(row - LSUP) * DIM;
        scale = 1.0f;
    }
    float x[6];
    float s = 0.f;
    #pragma unroll
    for (int i = 0; i < 6; ++i) { x[i] = src[lane + 64 * i]; s += x[i] * x[i]; }
    #pragma unroll
    for (int m = 1; m < 64; m <<= 1) s += __shfl_xor(s, m);
    float sc = scale / fmaxf(sqrtf(s), 1e-8f);
    #pragma unroll
    for (int i = 0; i < 6; ++i) dst[lane + 64 * i] = f2bf(x[i] * sc);
}

// ---------------------------------------------------------------------------
// Kernel 2: MFMA fused exp-sum GEMM, A-in-registers / full-image-B-in-LDS.
//   R[img][r] = sum_qs exp( (Kn[r] . Qimg[qs]) / T )    (K pre-scaled by 1/T)
// Block: 512 thr = 8 waves, each wave owns 48 rows (3 m-tiles), full K=384
// held in registers (36 v8s frags -> 144 VGPRs; ALL indexing constant so the
// array stays in registers — round-3's partial unroll spilled it to scratch).
// B staged in 3 col-passes of 80 qs.
// img<25 -> write bf16 to Rbf[b][w*1024+r] (masked rows -> 0)
// img>=25 -> write f32 to Rq[(img-25)*4900 + r]
// ---------------------------------------------------------------------------
#define QTILE 80
#define LDB   392   // LDS row stride in shorts (384+8): 16B aligned

__global__ __launch_bounds__(512, 2) void fused_gemm(
    const unsigned short* __restrict__ Kb,
    const unsigned short* __restrict__ Qall,
    float* __restrict__ Rq,
    unsigned short* __restrict__ Rbf)
{
    __shared__ __align__(16) unsigned short Bs[QTILE * LDB];  // 62720 B

    int t = threadIdx.x;
    int img = blockIdx.y;
    int wv = t >> 6, l = t & 63;
    int lo = l & 15, hi = l >> 4;
    const unsigned short* Q = Qall + (size_t)img * SEQ * DIM;
    int row0 = blockIdx.x * 384 + wv * 48;

    // --- load A fragments: 3 m-tiles x 12 k-tiles, once, from L2 ---
    v8s A[3][12];
    #pragma unroll
    for (int mm = 0; mm < 3; ++mm) {
        #pragma unroll
        for (int kk = 0; kk < 12; ++kk) {
            int gr = row0 + mm * 16 + lo;
            v8s z = {0, 0, 0, 0, 0, 0, 0, 0};
            A[mm][kk] = (gr < LSUP)
                ? *(const v8s*)(Kb + (size_t)gr * DIM + kk * 32 + hi * 8)
                : z;
        }
    }

    float srow[3][4];
    #pragma unroll
    for (int mm = 0; mm < 3; ++mm)
        #pragma unroll
        for (int j = 0; j < 4; ++j) srow[mm][j] = 0.f;

    for (int pass = 0; pass < 3; ++pass) {
        int qbase = pass * QTILE;
        int ntiles = (pass < 2) ? 5 : 3;
        int nstage = (pass < 2) ? QTILE : 48;
        // stage B tile
        for (int i = t; i < nstage * 48; i += 512) {
            int qs = i / 48, kc = i % 48;
            int gq = qbase + qs;
            float4 vv = make_float4(0.f, 0.f, 0.f, 0.f);
            if (gq < SEQ) vv = *(const float4*)(Q + (size_t)gq * DIM + kc * 8);
            *(float4*)(Bs + qs * LDB + kc * 8) = vv;
        }
        __syncthreads();

        for (int n = 0; n < ntiles; ++n) {
            v4f acc[3];
            #pragma unroll
            for (int mm = 0; mm < 3; ++mm) acc[mm] = (v4f){0.f, 0.f, 0.f, 0.f};
            const unsigned short* Bn = Bs + (n * 16 + lo) * LDB + hi * 8;
            #pragma unroll
            for (int kk = 0; kk < 12; ++kk) {       // FULL unroll: constant idx
                v8s bb = *(const v8s*)(Bn + kk * 32);
                acc[0] = __builtin_amdgcn_mfma_f32_16x16x32_bf16(A[0][kk], bb, acc[0], 0, 0, 0);
                acc[1] = __builtin_amdgcn_mfma_f32_16x16x32_bf16(A[1][kk], bb, acc[1], 0, 0, 0);
                acc[2] = __builtin_amdgcn_mfma_f32_16x16x32_bf16(A[2][kk], bb, acc[2], 0, 0, 0);
            }
            bool ok = (qbase + n * 16 + lo) < SEQ;
            #pragma unroll
            for (int mm = 0; mm < 3; ++mm)
                #pragma unroll
                for (int j = 0; j < 4; ++j)
                    srow[mm][j] += ok ? __expf(acc[mm][j]) : 0.f;
        }
        __syncthreads();
    }

    // reduce across the 16 column lanes (lo); C/D layout: col=lo, row=hi*4+j
    #pragma unroll
    for (int m = 1; m < 16; m <<= 1)
        #pragma unroll
        for (int mm = 0; mm < 3; ++mm)
            #pragma unroll
            for (int j = 0; j < 4; ++j)
                srow[mm][j] += __shfl_xor(srow[mm][j], m);

    if (lo == 0) {
        #pragma unroll
        for (int mm = 0; mm < 3; ++mm) {
            #pragma unroll
            for (int j = 0; j < 4; ++j) {
                int r = row0 + mm * 16 + hi * 4 + j;
                if (r < LSUP) {
                    float val = srow[mm][j];
                    if (img < NSUP) {
                        if (r / SEQ == img) val = 0.f;        // block-diag mask
                        int w = r / BLOCK_W, rr = r - w * BLOCK_W;
                        Rbf[(size_t)img * (NW * PADW) + w * PADW + rr] = f2bf(val);
                    } else {
                        Rq[(size_t)(img - NSUP) * LSUP + r] = val;
                    }
                }
            }
        }
    }
}

// ---------------------------------------------------------------------------
// Kernel 3: whole 15-step SGD in ONE 1024-thread block.
// Thread t<640 owns 8 consecutive rows of class w=t>>7 (r0=(t&127)*8);
// v,e live in REGISTERS for all 15 steps. R read per step as coalesced uint4
// from L2-hot Rbf (pads r in [980,1024) zeroed here; masked rows are 0).
//   e=exp(v/T); D[b][w]=sum e*R; cf=(D/sumD - onehot)*(INV_T/25)/D;
//   v -= LR * e * sum_b cf[b][w]*R[b][.]
// Each wave has uniform w (128 thr/class = 2 waves) -> shfl-reduced D parts.
// ---------------------------------------------------------------------------
__global__ __launch_bounds__(1024) void opt_all(unsigned short* __restrict__ Rbf,
                                                const int* __restrict__ labels,
                                                float* __restrict__ v_out) {
    __shared__ float D_s[128];
    __shared__ float cf_s[128];
    __shared__ float red[10][26];
    __shared__ int lab_s[NSUP];

    int t = threadIdx.x;
    int wave = t >> 6, lane = t & 63;

    // zero Rbf pads (GEMM never writes r in [980,1024))
    for (int i = t; i < NSUP * NW * (PADW - BLOCK_W); i += 1024) {
        int b = i / (NW * (PADW - BLOCK_W));
        int rem = i % (NW * (PADW - BLOCK_W));
        int w = rem / (PADW - BLOCK_W), r = BLOCK_W + rem % (PADW - BLOCK_W);
        Rbf[(size_t)b * (NW * PADW) + w * PADW + r] = 0;
    }
    if (t < NSUP) lab_s[t] = labels[t];
    __syncthreads();

    bool act = t < 640;
    int w  = t >> 7;            // class (uniform per wave)
    int r0 = (t & 127) * 8;
    const unsigned short* Rbase = Rbf + w * PADW + r0;

    float v8[8], e8[8];
    #pragma unroll
    for (int j = 0; j < 8; ++j) { v8[j] = 0.f; e8[j] = 1.f; }

    // D pass: part[b] = sum_j e8[j]*R[b][w][r0+j], reduce over wave, combine.
    auto dpass = [&]() {
        if (act) {
            for (int b = 0; b < NSUP; ++b) {
                uint4 u = *(const uint4*)(Rbase + (size_t)b * (NW * PADW));
                float f[8]; unpack8(u, f);
                float s = 0.f;
                #pragma unroll
                for (int j = 0; j < 8; ++j) s += e8[j] * f[j];
                #pragma unroll
                for (int m = 1; m < 64; m <<= 1) s += __shfl_xor(s, m);
                if (lane == 0) red[wave][b] = s;
            }
        }
        __syncthreads();
        if (t < 125) {
            int b = t / 5, ww = t % 5;
            D_s[t] = red[2 * ww][b] + red[2 * ww + 1][b];
        }
        __syncthreads();
    };

    dpass();    // D_0 (e = 1)

    for (int step = 0; step < OPT_STEPS; ++step) {
        if (t < 125) {
            int b = t / 5, ww = t % 5;
            float Dsum = D_s[b * 5 + 0] + D_s[b * 5 + 1] + D_s[b * 5 + 2]
                       + D_s[b * 5 + 3] + D_s[b * 5 + 4];
            float Dv = D_s[t];
            cf_s[t] = ((Dv / Dsum) - (ww == lab_s[b] ? 1.f : 0.f)) * (INV_T / 25.f) / Dv;
        }
        __syncthreads();

        if (act) {
            float g[8];
            #pragma unroll
            for (int j = 0; j < 8; ++j) g[j] = 0.f;
            for (int b = 0; b < NSUP; ++b) {
                uint4 u = *(const uint4*)(Rbase + (size_t)b * (NW * PADW));
                float f[8]; unpack8(u, f);
                float c = cf_s[b * 5 + w];
                #pragma unroll
                for (int j = 0; j < 8; ++j) g[j] += c * f[j];
            }
            #pragma unroll
            for (int j = 0; j < 8; ++j) {
                v8[j] -= LR_F * e8[j] * g[j];
                e8[j] = __expf(v8[j] * INV_T);
            }
        }
        __syncthreads();

        if (step < OPT_STEPS - 1) dpass();
    }

    if (act) {
        #pragma unroll
        for (int j = 0; j < 8; ++j)
            if (r0 + j < BLOCK_W) v_out[w * BLOCK_W + r0 + j] = v8[j];
    }
}

// ---------------------------------------------------------------------------
// Kernel 4: out[qb][w] = log( sum_{r in w} e^{v/T} * Rq[qb][w*980+r] )
// ---------------------------------------------------------------------------
__global__ __launch_bounds__(256) void final_pred(const float* __restrict__ Rq,
                                                  const float* __restrict__ v,
                                                  float* __restrict__ out) {
    __shared__ float wsum[4];
    int blk = blockIdx.x;           // qb*5 + w
    int qb = blk / 5, w = blk % 5;
    const float* R  = Rq + (size_t)qb * LSUP + w * BLOCK_W;
    const float* vb = v + w * BLOCK_W;
    int t = threadIdx.x;
    float p = 0.f;
    for (int i = t; i < BLOCK_W; i += 256) p += __expf(vb[i] * INV_T) * R[i];
    #pragma unroll
    for (int off = 32; off; off >>= 1) p += __shfl_down(p, off);
    if ((t & 63) == 0) wsum[t >> 6] = p;
    __syncthreads();
    if (t == 0) out[blk] = logf(wsum[0] + wsum[1] + wsum[2] + wsum[3]);
}

// ---------------------------------------------------------------------------
extern "C" void kernel_launch(void* const* d_in, const int* in_sizes, int n_in,
                              void* d_out, int out_size, void* d_ws, size_t ws_size,
                              hipStream_t stream) {
    const float* sup_key = (const float*)d_in[0];   // [25,196,384]
    const float* sup_qry = (const float*)d_in[1];   // [25,196,384]
    const float* qry     = (const float*)d_in[2];   // [75,196,384]
    const int*   labels  = (const int*)d_in[3];     // [25]
    float* out = (float*)d_out;                     // [75,5]

    char* ws = (char*)d_ws;
    size_t off = 0;
    auto take = [&](size_t bytes) {
        char* p = ws + off;
        off = (off + bytes + 255) & ~(size_t)255;
        return p;
    };
    unsigned short* Kb   = (unsigned short*)take((size_t)LSUP * DIM * 2);
    unsigned short* Qall = (unsigned short*)take((size_t)NIMG * SEQ * DIM * 2);
    float*          Rq   = (float*)take((size_t)NQRY * LSUP * 4);
    unsigned short* Rbf  = (unsigned short*)take((size_t)NSUP * NW * PADW * 2);
    float*          v    = (float*)take((size_t)LSUP * 4);

    int nrows = 2 * LSUP + NQRY * SEQ;              // 24500
    norm_all<<<(nrows + 3) / 4, 256, 0, stream>>>(sup_key, sup_qry, qry, Kb, Qall);

    fused_gemm<<<dim3(13, NIMG), 512, 0, stream>>>(Kb, Qall, Rq, Rbf);

    opt_all<<<1, 1024, 0, stream>>>(Rbf, labels, v);

    final_pred<<<NQRY * NW, 256, 0, stream>>>(Rq, v, out);
}